// Round 13
// baseline (413.074 us; speedup 1.0000x reference)
//
#include <hip/hip_runtime.h>
#include <math.h>

#define HD 128
#define GG 64
#define CSB 256   // colstat partial blocks

typedef __attribute__((ext_vector_type(8))) short short8;
typedef __attribute__((ext_vector_type(4))) float f32x4;

__device__ __forceinline__ float leaky(float x, float s) { return x > 0.f ? x : s * x; }

__device__ __forceinline__ unsigned short bf16_of(float f) {
    union { float f; unsigned u; } v; v.f = f;
    unsigned r = v.u + 0x7fffu + ((v.u >> 16) & 1u);
    return (unsigned short)(r >> 16);
}
__device__ __forceinline__ float f_of_bf16(unsigned short u) {
    union { unsigned u; float f; } v; v.u = ((unsigned)u) << 16;
    return v.f;
}

// ---------------- init: W->Wt bf16 transposed + zero bucket counters ----------------
__global__ void k_init(const float* __restrict__ Ws, unsigned short* __restrict__ Wt,
                       int* __restrict__ bcnt) {
    int i = blockIdx.x * 256 + threadIdx.x;
    if (i < 3 * 16384) {
        int l = i >> 14, rem = i & 16383;
        int nn = rem >> 7, k = rem & 127;
        Wt[i] = bf16_of(Ws[l * 16384 + k * 128 + nn]);
    }
    if (i < 513) bcnt[i] = 0;
}

// ================= barrier-free, LDS-free register-direct MFMA GEMM =============
// A-fragments AND B-fragments loaded directly from global in MFMA layouts.
// Wt (32KB) is L1/L2-resident, so B reads are cache hits. No __shared__, no
// __syncthreads: every wave fully independent. C stored directly; fused
// a_s/a_d row dots from fp32 accumulators.

// ---- variant A: fp32 input (layer 0, no norm) ----
__global__ __launch_bounds__(256) void k_gemm_a32(
    const float* __restrict__ A, const unsigned short* __restrict__ Wt,
    const float* __restrict__ att_s, const float* __restrict__ att_d,
    unsigned short* __restrict__ hWb, float* __restrict__ a_s, float* __restrict__ a_d,
    int n) {
    const int tid = threadIdx.x;
    const int base = blockIdx.x * 128;
    const int wave = tid >> 6, lane = tid & 63;
    const int m16 = lane & 15, quad = lane >> 4;

    short8 af[2][4];
#pragma unroll
    for (int rt = 0; rt < 2; ++rt) {
        int row = base + wave * 32 + rt * 16 + m16;
        row = (row < n) ? row : (n - 1);
        const float4* ap = (const float4*)(A + (size_t)row * 128);
#pragma unroll
        for (int kk = 0; kk < 4; ++kk) {
            float4 v0 = ap[kk * 8 + quad * 2];
            float4 v1 = ap[kk * 8 + quad * 2 + 1];
            union { short8 s; unsigned u[4]; } P;
            P.u[0] = (unsigned)bf16_of(v0.x) | ((unsigned)bf16_of(v0.y) << 16);
            P.u[1] = (unsigned)bf16_of(v0.z) | ((unsigned)bf16_of(v0.w) << 16);
            P.u[2] = (unsigned)bf16_of(v1.x) | ((unsigned)bf16_of(v1.y) << 16);
            P.u[3] = (unsigned)bf16_of(v1.z) | ((unsigned)bf16_of(v1.w) << 16);
            af[rt][kk] = P.s;
        }
    }

    f32x4 acc[2][8];
#pragma unroll
    for (int rt = 0; rt < 2; ++rt)
#pragma unroll
        for (int ct = 0; ct < 8; ++ct) acc[rt][ct] = (f32x4){0.f, 0.f, 0.f, 0.f};
#pragma unroll
    for (int kk = 0; kk < 4; ++kk) {
#pragma unroll
        for (int ct = 0; ct < 8; ++ct) {
            short8 bfr = *(const short8*)&Wt[(ct * 16 + m16) * 128 + kk * 32 + quad * 8];
            acc[0][ct] = __builtin_amdgcn_mfma_f32_16x16x32_bf16(af[0][kk], bfr, acc[0][ct], 0, 0, 0);
            acc[1][ct] = __builtin_amdgcn_mfma_f32_16x16x32_bf16(af[1][kk], bfr, acc[1][ct], 0, 0, 0);
        }
    }

#pragma unroll
    for (int rt = 0; rt < 2; ++rt) {
#pragma unroll
        for (int reg = 0; reg < 4; ++reg) {
            int gr = base + wave * 32 + rt * 16 + quad * 4 + reg;
            bool ok = gr < n;
            unsigned short* rowp = hWb + (size_t)gr * 128 + m16;
            float s = 0.f, dd = 0.f;
#pragma unroll
            for (int ct = 0; ct < 8; ++ct) {
                float v = acc[rt][ct][reg];
                int col = ct * 16 + m16;
                if (ok) rowp[ct * 16] = bf16_of(v);
                s = fmaf(v, att_s[col], s);
                dd = fmaf(v, att_d[col], dd);
            }
#pragma unroll
            for (int off = 1; off < 16; off <<= 1) {
                s += __shfl_xor(s, off, 64);
                dd += __shfl_xor(dd, off, 64);
            }
            if (m16 == 0 && ok) { a_s[gr] = s; a_d[gr] = dd; }
        }
    }
}

// ---- variant B: bf16 input + GraphNorm affine + leaky (layers 1,2) ----
__global__ __launch_bounds__(256) void k_gemm_a16(
    const unsigned short* __restrict__ Ab, const unsigned short* __restrict__ Wt,
    const float* __restrict__ att_s, const float* __restrict__ att_d,
    const float* __restrict__ alpha, const float* __restrict__ beta,
    unsigned short* __restrict__ hWb, float* __restrict__ a_s, float* __restrict__ a_d,
    int n) {
    const int tid = threadIdx.x;
    const int base = blockIdx.x * 128;
    const int wave = tid >> 6, lane = tid & 63;
    const int m16 = lane & 15, quad = lane >> 4;
    const float4* al4 = (const float4*)alpha;
    const float4* be4 = (const float4*)beta;

    short8 af[2][4];
#pragma unroll
    for (int rt = 0; rt < 2; ++rt) {
        int row = base + wave * 32 + rt * 16 + m16;
        row = (row < n) ? row : (n - 1);
        const uint4* ap = (const uint4*)(Ab + (size_t)row * 128);
#pragma unroll
        for (int kk = 0; kk < 4; ++kk) {
            uint4 raw = ap[kk * 4 + quad];
            int c4 = kk * 8 + quad * 2;
            float4 a0 = al4[c4], a1 = al4[c4 + 1];
            float4 b0 = be4[c4], b1 = be4[c4 + 1];
            float f0 = leaky(fmaf(f_of_bf16(raw.x & 0xffff), a0.x, b0.x), 0.01f);
            float f1 = leaky(fmaf(f_of_bf16(raw.x >> 16),    a0.y, b0.y), 0.01f);
            float f2 = leaky(fmaf(f_of_bf16(raw.y & 0xffff), a0.z, b0.z), 0.01f);
            float f3 = leaky(fmaf(f_of_bf16(raw.y >> 16),    a0.w, b0.w), 0.01f);
            float f4 = leaky(fmaf(f_of_bf16(raw.z & 0xffff), a1.x, b1.x), 0.01f);
            float f5 = leaky(fmaf(f_of_bf16(raw.z >> 16),    a1.y, b1.y), 0.01f);
            float f6 = leaky(fmaf(f_of_bf16(raw.w & 0xffff), a1.z, b1.z), 0.01f);
            float f7 = leaky(fmaf(f_of_bf16(raw.w >> 16),    a1.w, b1.w), 0.01f);
            union { short8 s; unsigned u[4]; } P;
            P.u[0] = (unsigned)bf16_of(f0) | ((unsigned)bf16_of(f1) << 16);
            P.u[1] = (unsigned)bf16_of(f2) | ((unsigned)bf16_of(f3) << 16);
            P.u[2] = (unsigned)bf16_of(f4) | ((unsigned)bf16_of(f5) << 16);
            P.u[3] = (unsigned)bf16_of(f6) | ((unsigned)bf16_of(f7) << 16);
            af[rt][kk] = P.s;
        }
    }

    f32x4 acc[2][8];
#pragma unroll
    for (int rt = 0; rt < 2; ++rt)
#pragma unroll
        for (int ct = 0; ct < 8; ++ct) acc[rt][ct] = (f32x4){0.f, 0.f, 0.f, 0.f};
#pragma unroll
    for (int kk = 0; kk < 4; ++kk) {
#pragma unroll
        for (int ct = 0; ct < 8; ++ct) {
            short8 bfr = *(const short8*)&Wt[(ct * 16 + m16) * 128 + kk * 32 + quad * 8];
            acc[0][ct] = __builtin_amdgcn_mfma_f32_16x16x32_bf16(af[0][kk], bfr, acc[0][ct], 0, 0, 0);
            acc[1][ct] = __builtin_amdgcn_mfma_f32_16x16x32_bf16(af[1][kk], bfr, acc[1][ct], 0, 0, 0);
        }
    }

#pragma unroll
    for (int rt = 0; rt < 2; ++rt) {
#pragma unroll
        for (int reg = 0; reg < 4; ++reg) {
            int gr = base + wave * 32 + rt * 16 + quad * 4 + reg;
            bool ok = gr < n;
            unsigned short* rowp = hWb + (size_t)gr * 128 + m16;
            float s = 0.f, dd = 0.f;
#pragma unroll
            for (int ct = 0; ct < 8; ++ct) {
                float v = acc[rt][ct][reg];
                int col = ct * 16 + m16;
                if (ok) rowp[ct * 16] = bf16_of(v);
                s = fmaf(v, att_s[col], s);
                dd = fmaf(v, att_d[col], dd);
            }
#pragma unroll
            for (int off = 1; off < 16; off <<= 1) {
                s += __shfl_xor(s, off, 64);
                dd += __shfl_xor(dd, off, 64);
            }
            if (m16 == 0 && ok) { a_s[gr] = s; a_d[gr] = dd; }
        }
    }
}

// ================= bucketed CSR build (LDS atomics, compact writes) =============
// Buckets of 512 nodes: bucket b = dst >> 9, local id = dst & 511.
// ebuf packs (local << 18) | src  (valid for n <= 262144).

__global__ __launch_bounds__(256) void k_bcount(const int* __restrict__ dst,
                                                int* __restrict__ bcnt, int e) {
    __shared__ int lh[512];
    const int tid = threadIdx.x;
    for (int t = tid; t < 512; t += 256) lh[t] = 0;
    __syncthreads();
    for (int i = blockIdx.x * 256 + tid; i < e; i += gridDim.x * 256)
        atomicAdd(&lh[dst[i] >> 9], 1);
    __syncthreads();
    for (int t = tid; t < 512; t += 256)
        if (lh[t]) atomicAdd(&bcnt[t], lh[t]);
}

__global__ void k_bscan(const int* __restrict__ bcnt, int* __restrict__ bbase,
                        int* __restrict__ bcur, int* __restrict__ offs,
                        int nbk, int n, int e) {
    __shared__ int s[512];
    int t = threadIdx.x;
    int v = (t < nbk) ? bcnt[t] : 0;
    s[t] = v;
    __syncthreads();
    for (int off = 1; off < 512; off <<= 1) {
        int u = (t >= off) ? s[t - off] : 0;
        __syncthreads();
        s[t] += u;
        __syncthreads();
    }
    if (t < nbk) { bbase[t] = s[t] - v; bcur[t] = s[t] - v; }
    if (t == 0) { bbase[nbk] = e; offs[n] = e; }
}

__global__ __launch_bounds__(256) void k_part(const int* __restrict__ src,
                                              const int* __restrict__ dst,
                                              int* __restrict__ bcur,
                                              int* __restrict__ ebuf, int e) {
    __shared__ int lh[512];
    __shared__ int lbase[512];
    const int tid = threadIdx.x;
    const int chunk = (e + gridDim.x - 1) / gridDim.x;
    const int i0 = blockIdx.x * chunk;
    const int i1 = min(e, i0 + chunk);
    for (int t = tid; t < 512; t += 256) lh[t] = 0;
    __syncthreads();
    for (int i = i0 + tid; i < i1; i += 256) atomicAdd(&lh[dst[i] >> 9], 1);
    __syncthreads();
    for (int t = tid; t < 512; t += 256) {
        int c = lh[t];
        lbase[t] = c ? atomicAdd(&bcur[t], c) : 0;
    }
    __syncthreads();
    for (int t = tid; t < 512; t += 256) lh[t] = 0;
    __syncthreads();
    for (int i = i0 + tid; i < i1; i += 256) {
        int d = dst[i];
        int b = d >> 9;
        int p = lbase[b] + atomicAdd(&lh[b], 1);
        ebuf[p] = ((d & 511) << 18) | src[i];
    }
}

__global__ __launch_bounds__(256) void k_bscatter(const int* __restrict__ ebuf,
                                                  const int* __restrict__ bbase,
                                                  int* __restrict__ offs,
                                                  int* __restrict__ esrc, int n) {
    const int b = blockIdx.x;
    const int tid = threadIdx.x;
    const int nb0 = b << 9;
    const int e0 = bbase[b], e1 = bbase[b + 1];
    __shared__ int cnt[512];
    __shared__ int sc[512];
    __shared__ int pos[512];
    for (int t = tid; t < 512; t += 256) cnt[t] = 0;
    __syncthreads();
    for (int i = e0 + tid; i < e1; i += 256) atomicAdd(&cnt[ebuf[i] >> 18], 1);
    __syncthreads();
    for (int t = tid; t < 512; t += 256) sc[t] = cnt[t];
    __syncthreads();
    for (int off = 1; off < 512; off <<= 1) {
        int t0 = tid, t1 = tid + 256;
        int v0 = (t0 >= off) ? sc[t0 - off] : 0;
        int v1 = sc[t1 - off];
        __syncthreads();
        sc[t0] += v0;
        sc[t1] += v1;
        __syncthreads();
    }
    for (int t = tid; t < 512; t += 256) pos[t] = e0 + sc[t] - cnt[t];
    __syncthreads();
    for (int t = tid; t < 512; t += 256) {
        int node = nb0 + t;
        if (node < n) offs[node] = pos[t];
    }
    __syncthreads();
    for (int i = e0 + tid; i < e1; i += 256) {
        int v = ebuf[i];
        int l = v >> 18;
        int p = atomicAdd(&pos[l], 1);
        esrc[p] = v & 0x3FFFF;
    }
}

// ---------------- fused attention softmax + aggregation -> bf16 h (R9 form) --------
__global__ __launch_bounds__(256) void k_agg(const unsigned short* __restrict__ hWb,
                                             const int* __restrict__ offs,
                                             const int* __restrict__ esrc,
                                             const float* __restrict__ a_s,
                                             const float* __restrict__ a_d,
                                             const float* __restrict__ bias,
                                             unsigned short* __restrict__ hb, int n) {
    int d = blockIdx.x * 4 + (threadIdx.x >> 6);
    int lane = threadIdx.x & 63;
    int q = lane >> 4;        // edge-slot group 0..3
    int l16 = lane & 15;      // 16B chunk within row
    if (d >= n) return;
    int p0 = offs[d], p1 = offs[d + 1];
    float ad = a_d[d];
    const uint4* hW8 = (const uint4*)hWb;
    float acc[8] = {0.f, 0.f, 0.f, 0.f, 0.f, 0.f, 0.f, 0.f};
    float ssum = 0.f;
    int s_cur = (p0 + q < p1) ? esrc[p0 + q] : 0;
    for (int p = p0 + q; p < p1; p += 4) {
        int s = s_cur;
        if (p + 4 < p1) s_cur = esrc[p + 4];
        float e = leaky(a_s[s] + ad, 0.2f);
        float ex = __expf(e);
        ssum += ex;
        uint4 raw = hW8[(size_t)s * 16 + l16];
        acc[0] = fmaf(ex, f_of_bf16(raw.x & 0xffff), acc[0]);
        acc[1] = fmaf(ex, f_of_bf16(raw.x >> 16),    acc[1]);
        acc[2] = fmaf(ex, f_of_bf16(raw.y & 0xffff), acc[2]);
        acc[3] = fmaf(ex, f_of_bf16(raw.y >> 16),    acc[3]);
        acc[4] = fmaf(ex, f_of_bf16(raw.z & 0xffff), acc[4]);
        acc[5] = fmaf(ex, f_of_bf16(raw.z >> 16),    acc[5]);
        acc[6] = fmaf(ex, f_of_bf16(raw.w & 0xffff), acc[6]);
        acc[7] = fmaf(ex, f_of_bf16(raw.w >> 16),    acc[7]);
    }
    ssum += __shfl_xor(ssum, 16, 64);
    ssum += __shfl_xor(ssum, 32, 64);
#pragma unroll
    for (int k = 0; k < 8; ++k) {
        acc[k] += __shfl_xor(acc[k], 16, 64);
        acc[k] += __shfl_xor(acc[k], 32, 64);
    }
    if (lane < 16) {
        float inv = 1.f / (ssum + 1e-16f);
        const float4* b4p = (const float4*)bias;
        float4 bb0 = b4p[l16 * 2], bb1 = b4p[l16 * 2 + 1];
        uint4 o;
        o.x = (unsigned)bf16_of(fmaf(acc[0], inv, bb0.x)) |
              ((unsigned)bf16_of(fmaf(acc[1], inv, bb0.y)) << 16);
        o.y = (unsigned)bf16_of(fmaf(acc[2], inv, bb0.z)) |
              ((unsigned)bf16_of(fmaf(acc[3], inv, bb0.w)) << 16);
        o.z = (unsigned)bf16_of(fmaf(acc[4], inv, bb1.x)) |
              ((unsigned)bf16_of(fmaf(acc[5], inv, bb1.y)) << 16);
        o.w = (unsigned)bf16_of(fmaf(acc[6], inv, bb1.z)) |
              ((unsigned)bf16_of(fmaf(acc[7], inv, bb1.w)) << 16);
        ((uint4*)hb)[(size_t)d * 16 + l16] = o;
    }
}

// ---------------- GraphNorm stats: partials only (no fence, no tail) ----------------
__global__ __launch_bounds__(256) void k_colstat6(const unsigned short* __restrict__ hb,
                                                  float* __restrict__ part, int n) {
    const uint4* h8 = (const uint4*)hb;    // 16 uint4 per 128-col row
    const int tid = threadIdx.x;
    const int total = n * 16;
    float s[8] = {0.f,0.f,0.f,0.f,0.f,0.f,0.f,0.f};
    float q[8] = {0.f,0.f,0.f,0.f,0.f,0.f,0.f,0.f};
    for (int i = blockIdx.x * 256 + tid; i < total; i += CSB * 256) {
        uint4 raw = h8[i];
        float v0 = f_of_bf16(raw.x & 0xffff), v1 = f_of_bf16(raw.x >> 16);
        float v2 = f_of_bf16(raw.y & 0xffff), v3 = f_of_bf16(raw.y >> 16);
        float v4 = f_of_bf16(raw.z & 0xffff), v5 = f_of_bf16(raw.z >> 16);
        float v6 = f_of_bf16(raw.w & 0xffff), v7 = f_of_bf16(raw.w >> 16);
        s[0] += v0; q[0] = fmaf(v0, v0, q[0]);
        s[1] += v1; q[1] = fmaf(v1, v1, q[1]);
        s[2] += v2; q[2] = fmaf(v2, v2, q[2]);
        s[3] += v3; q[3] = fmaf(v3, v3, q[3]);
        s[4] += v4; q[4] = fmaf(v4, v4, q[4]);
        s[5] += v5; q[5] = fmaf(v5, v5, q[5]);
        s[6] += v6; q[6] = fmaf(v6, v6, q[6]);
        s[7] += v7; q[7] = fmaf(v7, v7, q[7]);
    }
    __shared__ float ss[256][9];   // pad 9 -> conflict-free
    __shared__ float sq[256][9];
#pragma unroll
    for (int k = 0; k < 8; ++k) { ss[tid][k] = s[k]; sq[tid][k] = q[k]; }
    __syncthreads();
    if (tid < 128) {
        int c = tid >> 3, k = tid & 7;     // col = c*8 + k = tid
        float S = 0.f, Q = 0.f;
#pragma unroll
        for (int g = 0; g < 16; ++g) {
            S += ss[g * 16 + c][k];
            Q += sq[g * 16 + c][k];
        }
        part[blockIdx.x * 256 + tid] = S;
        part[blockIdx.x * 256 + 128 + tid] = Q;
    }
}

// ---------------- reduce partials + alpha/beta (separate launch = free visibility) --
__global__ __launch_bounds__(256) void k_colfin(const float* __restrict__ part,
                                                const float* __restrict__ w,
                                                const float* __restrict__ bb,
                                                const float* __restrict__ ms,
                                                float* __restrict__ alpha,
                                                float* __restrict__ beta, float inv_n) {
    int tid = threadIdx.x;
    float a0 = 0.f, a1 = 0.f, a2 = 0.f, a3 = 0.f;
    for (int b = 0; b < CSB; b += 4) {
        a0 += part[(b + 0) * 256 + tid];
        a1 += part[(b + 1) * 256 + tid];
        a2 += part[(b + 2) * 256 + tid];
        a3 += part[(b + 3) * 256 + tid];
    }
    __shared__ float fin[256];
    fin[tid] = (a0 + a1) + (a2 + a3);
    __syncthreads();
    if (tid < 128) {
        float mean = fin[tid] * inv_n;
        float ex2 = fin[128 + tid] * inv_n;
        float m2 = mean * ms[tid];
        float var = ex2 - 2.f * m2 * mean + m2 * m2;
        float a = w[tid] * rsqrtf(var + 1e-5f);
        alpha[tid] = a;
        beta[tid] = bb[tid] - m2 * a;
    }
}

// ---------------- global_add_pool: 4 blocks/graph, binary search, no atomics -------
__device__ __forceinline__ int lower_bound_i(const int* __restrict__ a, int n, int key) {
    int lo = 0, hi = n;
    while (lo < hi) {
        int mid = (lo + hi) >> 1;
        if (a[mid] < key) lo = mid + 1; else hi = mid;
    }
    return lo;
}

__global__ __launch_bounds__(256) void k_pool(const unsigned short* __restrict__ hb,
                                              const int* __restrict__ batch,
                                              float* __restrict__ pooled4, int n) {
    int g = blockIdx.x >> 2, t4 = blockIdx.x & 3;
    int lo = lower_bound_i(batch, n, g);
    int hi = lower_bound_i(batch, n, g + 1);
    int len = hi - lo;
    int q = (len + 3) >> 2;
    int r0 = lo + t4 * q;
    int r1 = min(r0 + q, hi);
    int c4 = threadIdx.x & 31, rg = threadIdx.x >> 5;
    const ushort4* h4 = (const ushort4*)hb;
    float4 acc = make_float4(0.f, 0.f, 0.f, 0.f);
    for (int r = r0 + rg; r < r1; r += 8) {
        ushort4 hv = h4[(size_t)r * 32 + c4];
        acc.x += f_of_bf16(hv.x);
        acc.y += f_of_bf16(hv.y);
        acc.z += f_of_bf16(hv.z);
        acc.w += f_of_bf16(hv.w);
    }
    __shared__ float4 sred[256];
    sred[threadIdx.x] = acc;
    __syncthreads();
    if (threadIdx.x < 32) {
        float4 S = sred[threadIdx.x];
#pragma unroll
        for (int k = 1; k < 8; ++k) {
            float4 a = sred[threadIdx.x + 32 * k];
            S.x += a.x; S.y += a.y; S.z += a.z; S.w += a.w;
        }
        ((float4*)pooled4)[(t4 * GG + g) * 32 + threadIdx.x] = S;
    }
}

// ---------------- final MLP (sums the 4 pool partials) ----------------
__global__ __launch_bounds__(128) void k_mlp(const float* __restrict__ pooled4,
                                             const float* __restrict__ W1,
                                             const float* __restrict__ b1,
                                             const float* __restrict__ W2,
                                             const float* __restrict__ b2,
                                             float* __restrict__ out) {
    __shared__ float pr[HD];
    __shared__ float zs[HD];
    int g = blockIdx.x, t = threadIdx.x;
    float pv = 0.f;
#pragma unroll
    for (int k = 0; k < 4; ++k) pv += pooled4[(k * GG + g) * HD + t];
    pr[t] = pv;
    __syncthreads();
    float acc = b1[t];
#pragma unroll 8
    for (int k = 0; k < HD; ++k) acc = fmaf(pr[k], W1[k * HD + t], acc);
    zs[t] = leaky(acc, 0.01f);
    __syncthreads();
    if (t < 64) {
        float a2 = b2[t];
#pragma unroll 8
        for (int k = 0; k < HD; ++k) a2 = fmaf(zs[k], W2[k * 64 + t], a2);
        out[g * 64 + t] = a2;
    }
}

extern "C" void kernel_launch(void* const* d_in, const int* in_sizes, int n_in,
                              void* d_out, int out_size, void* d_ws, size_t ws_size,
                              hipStream_t stream) {
    const float* x        = (const float*)d_in[0];
    const int*   ei       = (const int*)d_in[1];
    const int*   batch    = (const int*)d_in[2];
    const float* Ws       = (const float*)d_in[3];
    const float* att_src  = (const float*)d_in[4];
    const float* att_dst  = (const float*)d_in[5];
    const float* conv_bias= (const float*)d_in[6];
    const float* gn_w     = (const float*)d_in[7];
    const float* gn_b     = (const float*)d_in[8];
    const float* gn_ms    = (const float*)d_in[9];
    const float* W1       = (const float*)d_in[10];
    const float* b1       = (const float*)d_in[11];
    const float* W2       = (const float*)d_in[12];
    const float* b2       = (const float*)d_in[13];
    float* out = (float*)d_out;

    const int n = in_sizes[2];       // 100000
    const int e = in_sizes[1] / 2;   // 600000
    const int* src = ei;
    const int* dst = ei + e;
    const int nbk = (n + 511) >> 9;  // 512-node buckets (n <= 262144 for ebuf packing)

    char* ws = (char*)d_ws;
    unsigned short* hWb = (unsigned short*)ws;                    // n*128 bf16
    unsigned short* hb  = hWb + (size_t)n * HD;                   // n*128 bf16
    float* a_s    = (float*)(hb + (size_t)n * HD);                // n
    float* a_d    = a_s + n;                                      // n
    float* alpha  = a_d + n;                                      // 128
    float* beta   = alpha + HD;                                   // 128
    float* pooled4= beta + HD;                                    // 4*GG*128
    float* part   = pooled4 + 4 * GG * HD;                        // CSB*256
    unsigned short* Wt = (unsigned short*)(part + CSB * 256);     // 3*128*128
    int* offs     = (int*)(Wt + 3 * 16384);                       // n+1
    int* esrc     = offs + n + 1;                                 // e
    int* ebuf     = esrc + e;                                     // e
    int* bcnt     = ebuf + e;                                     // 513
    int* bbase    = bcnt + 513;                                   // 514
    int* bcur     = bbase + 514;                                  // 513

    // ---- init (weights->bf16 transposed + zero bucket counters) ----
    k_init<<<192, 256, 0, stream>>>(Ws, Wt, bcnt);
    // ---- bucketed CSR build ----
    k_bcount<<<256, 256, 0, stream>>>(dst, bcnt, e);
    k_bscan<<<1, 512, 0, stream>>>(bcnt, bbase, bcur, offs, nbk, n, e);
    k_part<<<256, 256, 0, stream>>>(src, dst, bcur, ebuf, e);
    k_bscatter<<<nbk, 256, 0, stream>>>(ebuf, bbase, offs, esrc, n);

    // ---- GAT layers ----
    for (int l = 0; l < 3; ++l) {
        if (l == 0) {
            k_gemm_a32<<<(n + 127) / 128, 256, 0, stream>>>(
                x, Wt, att_src, att_dst, hWb, a_s, a_d, n);
        } else {
            k_gemm_a16<<<(n + 127) / 128, 256, 0, stream>>>(
                hb, Wt + l * 16384, att_src + l * HD, att_dst + l * HD,
                alpha, beta, hWb, a_s, a_d, n);
        }
        k_agg<<<(n + 3) / 4, 256, 0, stream>>>(hWb, offs, esrc, a_s, a_d,
                                               conv_bias + l * HD, hb, n);
        if (l < 2) {
            k_colstat6<<<CSB, 256, 0, stream>>>(hb, part, n);
            k_colfin<<<1, 256, 0, stream>>>(part, gn_w + l * HD, gn_b + l * HD,
                                            gn_ms + l * HD, alpha, beta, 1.0f / n);
        }
    }

    // ---- pool + MLP ----
    k_pool<<<4 * GG, 256, 0, stream>>>(hb, batch, pooled4, n);
    k_mlp<<<GG, HD, 0, stream>>>(pooled4, W1, b1, W2, b2, out);
}

// Round 14
// 378.774 us; speedup vs baseline: 1.0906x; 1.0906x over previous
//
#include <hip/hip_runtime.h>
#include <math.h>

#define HD 128
#define GG 64
#define CSB 256   // colstat partial blocks

typedef __attribute__((ext_vector_type(8))) short short8;
typedef __attribute__((ext_vector_type(4))) float f32x4;

__device__ __forceinline__ float leaky(float x, float s) { return x > 0.f ? x : s * x; }

__device__ __forceinline__ unsigned short bf16_of(float f) {
    union { float f; unsigned u; } v; v.f = f;
    unsigned r = v.u + 0x7fffu + ((v.u >> 16) & 1u);
    return (unsigned short)(r >> 16);
}
__device__ __forceinline__ float f_of_bf16(unsigned short u) {
    union { unsigned u; float f; } v; v.u = ((unsigned)u) << 16;
    return v.f;
}

// XOR-swizzled LDS addressing for the 128x128 bf16 W tile (16B chunks).
__device__ __forceinline__ int sw(int row, int chunk) {
    return row * 128 + ((chunk ^ (row & 15)) << 3);
}

// ---------------- init: W->Wt bf16 transposed + zero bucket counters ----------------
__global__ void k_init(const float* __restrict__ Ws, unsigned short* __restrict__ Wt,
                       int* __restrict__ bcnt) {
    int i = blockIdx.x * 256 + threadIdx.x;
    if (i < 3 * 16384) {
        int l = i >> 14, rem = i & 16383;
        int nn = rem >> 7, k = rem & 127;
        Wt[i] = bf16_of(Ws[l * 16384 + k * 128 + nn]);
    }
    if (i < 513) bcnt[i] = 0;
}

// ================= register-A + LDS-B MFMA GEMM, 64-row blocks =============
// rt=1: each wave owns 16 rows -> ~80 VGPR, 32KB LDS -> 5 blocks/CU (20 waves).
// A-fragments register-direct from global (issued before the single barrier);
// B staged in LDS (swizzled). C stored directly; fused a_s/a_d row dots.

// ---- variant A: fp32 input (layer 0, no norm) ----
__global__ __launch_bounds__(256) void k_gemm_a32(
    const float* __restrict__ A, const unsigned short* __restrict__ Wt,
    const float* __restrict__ att_s, const float* __restrict__ att_d,
    unsigned short* __restrict__ hWb, float* __restrict__ a_s, float* __restrict__ a_d,
    int n) {
    __shared__ unsigned short Bs[128 * 128];
    const int tid = threadIdx.x;
    const int base = blockIdx.x * 64;

    const uint4* Wt4 = (const uint4*)Wt;
    uint4* Bs4 = (uint4*)Bs;
#pragma unroll
    for (int j = 0; j < 8; ++j) {
        int flat = tid + j * 256;
        int col = flat >> 4, c8 = flat & 15;
        Bs4[(col << 4) + (c8 ^ (col & 15))] = Wt4[flat];
    }

    const int wave = tid >> 6, lane = tid & 63;
    const int m16 = lane & 15, quad = lane >> 4;

    short8 af[4];
    {
        int row = base + wave * 16 + m16;
        row = (row < n) ? row : (n - 1);
        const float4* ap = (const float4*)(A + (size_t)row * 128);
#pragma unroll
        for (int kk = 0; kk < 4; ++kk) {
            float4 v0 = ap[kk * 8 + quad * 2];
            float4 v1 = ap[kk * 8 + quad * 2 + 1];
            union { short8 s; unsigned u[4]; } P;
            P.u[0] = (unsigned)bf16_of(v0.x) | ((unsigned)bf16_of(v0.y) << 16);
            P.u[1] = (unsigned)bf16_of(v0.z) | ((unsigned)bf16_of(v0.w) << 16);
            P.u[2] = (unsigned)bf16_of(v1.x) | ((unsigned)bf16_of(v1.y) << 16);
            P.u[3] = (unsigned)bf16_of(v1.z) | ((unsigned)bf16_of(v1.w) << 16);
            af[kk] = P.s;
        }
    }
    __syncthreads();

    f32x4 acc[8];
#pragma unroll
    for (int ct = 0; ct < 8; ++ct) acc[ct] = (f32x4){0.f, 0.f, 0.f, 0.f};
#pragma unroll
    for (int kk = 0; kk < 4; ++kk) {
#pragma unroll
        for (int ct = 0; ct < 8; ++ct) {
            short8 bfr = *(const short8*)&Bs[sw(ct * 16 + m16, kk * 4 + quad)];
            acc[ct] = __builtin_amdgcn_mfma_f32_16x16x32_bf16(af[kk], bfr, acc[ct], 0, 0, 0);
        }
    }

#pragma unroll
    for (int reg = 0; reg < 4; ++reg) {
        int gr = base + wave * 16 + quad * 4 + reg;
        bool ok = gr < n;
        unsigned short* rowp = hWb + (size_t)gr * 128 + m16;
        float s = 0.f, dd = 0.f;
#pragma unroll
        for (int ct = 0; ct < 8; ++ct) {
            float v = acc[ct][reg];
            int col = ct * 16 + m16;
            if (ok) rowp[ct * 16] = bf16_of(v);
            s = fmaf(v, att_s[col], s);
            dd = fmaf(v, att_d[col], dd);
        }
#pragma unroll
        for (int off = 1; off < 16; off <<= 1) {
            s += __shfl_xor(s, off, 64);
            dd += __shfl_xor(dd, off, 64);
        }
        if (m16 == 0 && ok) { a_s[gr] = s; a_d[gr] = dd; }
    }
}

// ---- variant B: bf16 input + GraphNorm affine + leaky (layers 1,2) ----
__global__ __launch_bounds__(256) void k_gemm_a16(
    const unsigned short* __restrict__ Ab, const unsigned short* __restrict__ Wt,
    const float* __restrict__ att_s, const float* __restrict__ att_d,
    const float* __restrict__ alpha, const float* __restrict__ beta,
    unsigned short* __restrict__ hWb, float* __restrict__ a_s, float* __restrict__ a_d,
    int n) {
    __shared__ unsigned short Bs[128 * 128];
    const int tid = threadIdx.x;
    const int base = blockIdx.x * 64;

    const uint4* Wt4 = (const uint4*)Wt;
    uint4* Bs4 = (uint4*)Bs;
#pragma unroll
    for (int j = 0; j < 8; ++j) {
        int flat = tid + j * 256;
        int col = flat >> 4, c8 = flat & 15;
        Bs4[(col << 4) + (c8 ^ (col & 15))] = Wt4[flat];
    }

    const int wave = tid >> 6, lane = tid & 63;
    const int m16 = lane & 15, quad = lane >> 4;
    const float4* al4 = (const float4*)alpha;
    const float4* be4 = (const float4*)beta;

    short8 af[4];
    {
        int row = base + wave * 16 + m16;
        row = (row < n) ? row : (n - 1);
        const uint4* ap = (const uint4*)(Ab + (size_t)row * 128);
#pragma unroll
        for (int kk = 0; kk < 4; ++kk) {
            uint4 raw = ap[kk * 4 + quad];
            int c4 = kk * 8 + quad * 2;
            float4 a0 = al4[c4], a1 = al4[c4 + 1];
            float4 b0 = be4[c4], b1 = be4[c4 + 1];
            float f0 = leaky(fmaf(f_of_bf16(raw.x & 0xffff), a0.x, b0.x), 0.01f);
            float f1 = leaky(fmaf(f_of_bf16(raw.x >> 16),    a0.y, b0.y), 0.01f);
            float f2 = leaky(fmaf(f_of_bf16(raw.y & 0xffff), a0.z, b0.z), 0.01f);
            float f3 = leaky(fmaf(f_of_bf16(raw.y >> 16),    a0.w, b0.w), 0.01f);
            float f4 = leaky(fmaf(f_of_bf16(raw.z & 0xffff), a1.x, b1.x), 0.01f);
            float f5 = leaky(fmaf(f_of_bf16(raw.z >> 16),    a1.y, b1.y), 0.01f);
            float f6 = leaky(fmaf(f_of_bf16(raw.w & 0xffff), a1.z, b1.z), 0.01f);
            float f7 = leaky(fmaf(f_of_bf16(raw.w >> 16),    a1.w, b1.w), 0.01f);
            union { short8 s; unsigned u[4]; } P;
            P.u[0] = (unsigned)bf16_of(f0) | ((unsigned)bf16_of(f1) << 16);
            P.u[1] = (unsigned)bf16_of(f2) | ((unsigned)bf16_of(f3) << 16);
            P.u[2] = (unsigned)bf16_of(f4) | ((unsigned)bf16_of(f5) << 16);
            P.u[3] = (unsigned)bf16_of(f6) | ((unsigned)bf16_of(f7) << 16);
            af[kk] = P.s;
        }
    }
    __syncthreads();

    f32x4 acc[8];
#pragma unroll
    for (int ct = 0; ct < 8; ++ct) acc[ct] = (f32x4){0.f, 0.f, 0.f, 0.f};
#pragma unroll
    for (int kk = 0; kk < 4; ++kk) {
#pragma unroll
        for (int ct = 0; ct < 8; ++ct) {
            short8 bfr = *(const short8*)&Bs[sw(ct * 16 + m16, kk * 4 + quad)];
            acc[ct] = __builtin_amdgcn_mfma_f32_16x16x32_bf16(af[kk], bfr, acc[ct], 0, 0, 0);
        }
    }

#pragma unroll
    for (int reg = 0; reg < 4; ++reg) {
        int gr = base + wave * 16 + quad * 4 + reg;
        bool ok = gr < n;
        unsigned short* rowp = hWb + (size_t)gr * 128 + m16;
        float s = 0.f, dd = 0.f;
#pragma unroll
        for (int ct = 0; ct < 8; ++ct) {
            float v = acc[ct][reg];
            int col = ct * 16 + m16;
            if (ok) rowp[ct * 16] = bf16_of(v);
            s = fmaf(v, att_s[col], s);
            dd = fmaf(v, att_d[col], dd);
        }
#pragma unroll
        for (int off = 1; off < 16; off <<= 1) {
            s += __shfl_xor(s, off, 64);
            dd += __shfl_xor(dd, off, 64);
        }
        if (m16 == 0 && ok) { a_s[gr] = s; a_d[gr] = dd; }
    }
}

// ================= bucketed CSR build (LDS atomics, compact writes) =============
// Buckets of 512 nodes: bucket b = dst >> 9, local id = dst & 511.
// ebuf packs (local << 18) | src  (valid for n <= 262144).

__global__ __launch_bounds__(256) void k_bcount(const int* __restrict__ dst,
                                                int* __restrict__ bcnt, int e) {
    __shared__ int lh[512];
    const int tid = threadIdx.x;
    for (int t = tid; t < 512; t += 256) lh[t] = 0;
    __syncthreads();
    for (int i = blockIdx.x * 256 + tid; i < e; i += gridDim.x * 256)
        atomicAdd(&lh[dst[i] >> 9], 1);
    __syncthreads();
    for (int t = tid; t < 512; t += 256)
        if (lh[t]) atomicAdd(&bcnt[t], lh[t]);
}

__global__ void k_bscan(const int* __restrict__ bcnt, int* __restrict__ bbase,
                        int* __restrict__ bcur, int* __restrict__ offs,
                        int nbk, int n, int e) {
    __shared__ int s[512];
    int t = threadIdx.x;
    int v = (t < nbk) ? bcnt[t] : 0;
    s[t] = v;
    __syncthreads();
    for (int off = 1; off < 512; off <<= 1) {
        int u = (t >= off) ? s[t - off] : 0;
        __syncthreads();
        s[t] += u;
        __syncthreads();
    }
    if (t < nbk) { bbase[t] = s[t] - v; bcur[t] = s[t] - v; }
    if (t == 0) { bbase[nbk] = e; offs[n] = e; }
}

__global__ __launch_bounds__(256) void k_part(const int* __restrict__ src,
                                              const int* __restrict__ dst,
                                              int* __restrict__ bcur,
                                              int* __restrict__ ebuf, int e) {
    __shared__ int lh[512];
    __shared__ int lbase[512];
    const int tid = threadIdx.x;
    const int chunk = (e + gridDim.x - 1) / gridDim.x;
    const int i0 = blockIdx.x * chunk;
    const int i1 = min(e, i0 + chunk);
    for (int t = tid; t < 512; t += 256) lh[t] = 0;
    __syncthreads();
    for (int i = i0 + tid; i < i1; i += 256) atomicAdd(&lh[dst[i] >> 9], 1);
    __syncthreads();
    for (int t = tid; t < 512; t += 256) {
        int c = lh[t];
        lbase[t] = c ? atomicAdd(&bcur[t], c) : 0;
    }
    __syncthreads();
    for (int t = tid; t < 512; t += 256) lh[t] = 0;
    __syncthreads();
    for (int i = i0 + tid; i < i1; i += 256) {
        int d = dst[i];
        int b = d >> 9;
        int p = lbase[b] + atomicAdd(&lh[b], 1);
        ebuf[p] = ((d & 511) << 18) | src[i];
    }
}

__global__ __launch_bounds__(256) void k_bscatter(const int* __restrict__ ebuf,
                                                  const int* __restrict__ bbase,
                                                  int* __restrict__ offs,
                                                  int* __restrict__ esrc, int n) {
    const int b = blockIdx.x;
    const int tid = threadIdx.x;
    const int nb0 = b << 9;
    const int e0 = bbase[b], e1 = bbase[b + 1];
    __shared__ int cnt[512];
    __shared__ int sc[512];
    __shared__ int pos[512];
    for (int t = tid; t < 512; t += 256) cnt[t] = 0;
    __syncthreads();
    for (int i = e0 + tid; i < e1; i += 256) atomicAdd(&cnt[ebuf[i] >> 18], 1);
    __syncthreads();
    for (int t = tid; t < 512; t += 256) sc[t] = cnt[t];
    __syncthreads();
    for (int off = 1; off < 512; off <<= 1) {
        int t0 = tid, t1 = tid + 256;
        int v0 = (t0 >= off) ? sc[t0 - off] : 0;
        int v1 = sc[t1 - off];
        __syncthreads();
        sc[t0] += v0;
        sc[t1] += v1;
        __syncthreads();
    }
    for (int t = tid; t < 512; t += 256) pos[t] = e0 + sc[t] - cnt[t];
    __syncthreads();
    for (int t = tid; t < 512; t += 256) {
        int node = nb0 + t;
        if (node < n) offs[node] = pos[t];
    }
    __syncthreads();
    for (int i = e0 + tid; i < e1; i += 256) {
        int v = ebuf[i];
        int l = v >> 18;
        int p = atomicAdd(&pos[l], 1);
        esrc[p] = v & 0x3FFFF;
    }
}

// ---------------- fused attention softmax + aggregation -> bf16 h (R9 form) --------
__global__ __launch_bounds__(256) void k_agg(const unsigned short* __restrict__ hWb,
                                             const int* __restrict__ offs,
                                             const int* __restrict__ esrc,
                                             const float* __restrict__ a_s,
                                             const float* __restrict__ a_d,
                                             const float* __restrict__ bias,
                                             unsigned short* __restrict__ hb, int n) {
    int d = blockIdx.x * 4 + (threadIdx.x >> 6);
    int lane = threadIdx.x & 63;
    int q = lane >> 4;        // edge-slot group 0..3
    int l16 = lane & 15;      // 16B chunk within row
    if (d >= n) return;
    int p0 = offs[d], p1 = offs[d + 1];
    float ad = a_d[d];
    const uint4* hW8 = (const uint4*)hWb;
    float acc[8] = {0.f, 0.f, 0.f, 0.f, 0.f, 0.f, 0.f, 0.f};
    float ssum = 0.f;
    int s_cur = (p0 + q < p1) ? esrc[p0 + q] : 0;
    for (int p = p0 + q; p < p1; p += 4) {
        int s = s_cur;
        if (p + 4 < p1) s_cur = esrc[p + 4];
        float e = leaky(a_s[s] + ad, 0.2f);
        float ex = __expf(e);
        ssum += ex;
        uint4 raw = hW8[(size_t)s * 16 + l16];
        acc[0] = fmaf(ex, f_of_bf16(raw.x & 0xffff), acc[0]);
        acc[1] = fmaf(ex, f_of_bf16(raw.x >> 16),    acc[1]);
        acc[2] = fmaf(ex, f_of_bf16(raw.y & 0xffff), acc[2]);
        acc[3] = fmaf(ex, f_of_bf16(raw.y >> 16),    acc[3]);
        acc[4] = fmaf(ex, f_of_bf16(raw.z & 0xffff), acc[4]);
        acc[5] = fmaf(ex, f_of_bf16(raw.z >> 16),    acc[5]);
        acc[6] = fmaf(ex, f_of_bf16(raw.w & 0xffff), acc[6]);
        acc[7] = fmaf(ex, f_of_bf16(raw.w >> 16),    acc[7]);
    }
    ssum += __shfl_xor(ssum, 16, 64);
    ssum += __shfl_xor(ssum, 32, 64);
#pragma unroll
    for (int k = 0; k < 8; ++k) {
        acc[k] += __shfl_xor(acc[k], 16, 64);
        acc[k] += __shfl_xor(acc[k], 32, 64);
    }
    if (lane < 16) {
        float inv = 1.f / (ssum + 1e-16f);
        const float4* b4p = (const float4*)bias;
        float4 bb0 = b4p[l16 * 2], bb1 = b4p[l16 * 2 + 1];
        uint4 o;
        o.x = (unsigned)bf16_of(fmaf(acc[0], inv, bb0.x)) |
              ((unsigned)bf16_of(fmaf(acc[1], inv, bb0.y)) << 16);
        o.y = (unsigned)bf16_of(fmaf(acc[2], inv, bb0.z)) |
              ((unsigned)bf16_of(fmaf(acc[3], inv, bb0.w)) << 16);
        o.z = (unsigned)bf16_of(fmaf(acc[4], inv, bb1.x)) |
              ((unsigned)bf16_of(fmaf(acc[5], inv, bb1.y)) << 16);
        o.w = (unsigned)bf16_of(fmaf(acc[6], inv, bb1.z)) |
              ((unsigned)bf16_of(fmaf(acc[7], inv, bb1.w)) << 16);
        ((uint4*)hb)[(size_t)d * 16 + l16] = o;
    }
}

// ---------------- GraphNorm stats: partials only (no fence, no tail) ----------------
__global__ __launch_bounds__(256) void k_colstat6(const unsigned short* __restrict__ hb,
                                                  float* __restrict__ part, int n) {
    const uint4* h8 = (const uint4*)hb;    // 16 uint4 per 128-col row
    const int tid = threadIdx.x;
    const int total = n * 16;
    float s[8] = {0.f,0.f,0.f,0.f,0.f,0.f,0.f,0.f};
    float q[8] = {0.f,0.f,0.f,0.f,0.f,0.f,0.f,0.f};
    for (int i = blockIdx.x * 256 + tid; i < total; i += CSB * 256) {
        uint4 raw = h8[i];
        float v0 = f_of_bf16(raw.x & 0xffff), v1 = f_of_bf16(raw.x >> 16);
        float v2 = f_of_bf16(raw.y & 0xffff), v3 = f_of_bf16(raw.y >> 16);
        float v4 = f_of_bf16(raw.z & 0xffff), v5 = f_of_bf16(raw.z >> 16);
        float v6 = f_of_bf16(raw.w & 0xffff), v7 = f_of_bf16(raw.w >> 16);
        s[0] += v0; q[0] = fmaf(v0, v0, q[0]);
        s[1] += v1; q[1] = fmaf(v1, v1, q[1]);
        s[2] += v2; q[2] = fmaf(v2, v2, q[2]);
        s[3] += v3; q[3] = fmaf(v3, v3, q[3]);
        s[4] += v4; q[4] = fmaf(v4, v4, q[4]);
        s[5] += v5; q[5] = fmaf(v5, v5, q[5]);
        s[6] += v6; q[6] = fmaf(v6, v6, q[6]);
        s[7] += v7; q[7] = fmaf(v7, v7, q[7]);
    }
    __shared__ float ss[256][9];   // pad 9 -> conflict-free
    __shared__ float sq[256][9];
#pragma unroll
    for (int k = 0; k < 8; ++k) { ss[tid][k] = s[k]; sq[tid][k] = q[k]; }
    __syncthreads();
    if (tid < 128) {
        int c = tid >> 3, k = tid & 7;     // col = c*8 + k = tid
        float S = 0.f, Q = 0.f;
#pragma unroll
        for (int g = 0; g < 16; ++g) {
            S += ss[g * 16 + c][k];
            Q += sq[g * 16 + c][k];
        }
        part[blockIdx.x * 256 + tid] = S;
        part[blockIdx.x * 256 + 128 + tid] = Q;
    }
}

// ---------------- reduce partials + alpha/beta (separate launch = free visibility) --
__global__ __launch_bounds__(256) void k_colfin(const float* __restrict__ part,
                                                const float* __restrict__ w,
                                                const float* __restrict__ bb,
                                                const float* __restrict__ ms,
                                                float* __restrict__ alpha,
                                                float* __restrict__ beta, float inv_n) {
    int tid = threadIdx.x;
    float a0 = 0.f, a1 = 0.f, a2 = 0.f, a3 = 0.f;
    for (int b = 0; b < CSB; b += 4) {
        a0 += part[(b + 0) * 256 + tid];
        a1 += part[(b + 1) * 256 + tid];
        a2 += part[(b + 2) * 256 + tid];
        a3 += part[(b + 3) * 256 + tid];
    }
    __shared__ float fin[256];
    fin[tid] = (a0 + a1) + (a2 + a3);
    __syncthreads();
    if (tid < 128) {
        float mean = fin[tid] * inv_n;
        float ex2 = fin[128 + tid] * inv_n;
        float m2 = mean * ms[tid];
        float var = ex2 - 2.f * m2 * mean + m2 * m2;
        float a = w[tid] * rsqrtf(var + 1e-5f);
        alpha[tid] = a;
        beta[tid] = bb[tid] - m2 * a;
    }
}

// ---------------- global_add_pool: 4 blocks/graph, binary search, no atomics -------
__device__ __forceinline__ int lower_bound_i(const int* __restrict__ a, int n, int key) {
    int lo = 0, hi = n;
    while (lo < hi) {
        int mid = (lo + hi) >> 1;
        if (a[mid] < key) lo = mid + 1; else hi = mid;
    }
    return lo;
}

__global__ __launch_bounds__(256) void k_pool(const unsigned short* __restrict__ hb,
                                              const int* __restrict__ batch,
                                              float* __restrict__ pooled4, int n) {
    int g = blockIdx.x >> 2, t4 = blockIdx.x & 3;
    int lo = lower_bound_i(batch, n, g);
    int hi = lower_bound_i(batch, n, g + 1);
    int len = hi - lo;
    int q = (len + 3) >> 2;
    int r0 = lo + t4 * q;
    int r1 = min(r0 + q, hi);
    int c4 = threadIdx.x & 31, rg = threadIdx.x >> 5;
    const ushort4* h4 = (const ushort4*)hb;
    float4 acc = make_float4(0.f, 0.f, 0.f, 0.f);
    for (int r = r0 + rg; r < r1; r += 8) {
        ushort4 hv = h4[(size_t)r * 32 + c4];
        acc.x += f_of_bf16(hv.x);
        acc.y += f_of_bf16(hv.y);
        acc.z += f_of_bf16(hv.z);
        acc.w += f_of_bf16(hv.w);
    }
    __shared__ float4 sred[256];
    sred[threadIdx.x] = acc;
    __syncthreads();
    if (threadIdx.x < 32) {
        float4 S = sred[threadIdx.x];
#pragma unroll
        for (int k = 1; k < 8; ++k) {
            float4 a = sred[threadIdx.x + 32 * k];
            S.x += a.x; S.y += a.y; S.z += a.z; S.w += a.w;
        }
        ((float4*)pooled4)[(t4 * GG + g) * 32 + threadIdx.x] = S;
    }
}

// ---------------- final MLP (sums the 4 pool partials) ----------------
__global__ __launch_bounds__(128) void k_mlp(const float* __restrict__ pooled4,
                                             const float* __restrict__ W1,
                                             const float* __restrict__ b1,
                                             const float* __restrict__ W2,
                                             const float* __restrict__ b2,
                                             float* __restrict__ out) {
    __shared__ float pr[HD];
    __shared__ float zs[HD];
    int g = blockIdx.x, t = threadIdx.x;
    float pv = 0.f;
#pragma unroll
    for (int k = 0; k < 4; ++k) pv += pooled4[(k * GG + g) * HD + t];
    pr[t] = pv;
    __syncthreads();
    float acc = b1[t];
#pragma unroll 8
    for (int k = 0; k < HD; ++k) acc = fmaf(pr[k], W1[k * HD + t], acc);
    zs[t] = leaky(acc, 0.01f);
    __syncthreads();
    if (t < 64) {
        float a2 = b2[t];
#pragma unroll 8
        for (int k = 0; k < HD; ++k) a2 = fmaf(zs[k], W2[k * 64 + t], a2);
        out[g * 64 + t] = a2;
    }
}

extern "C" void kernel_launch(void* const* d_in, const int* in_sizes, int n_in,
                              void* d_out, int out_size, void* d_ws, size_t ws_size,
                              hipStream_t stream) {
    const float* x        = (const float*)d_in[0];
    const int*   ei       = (const int*)d_in[1];
    const int*   batch    = (const int*)d_in[2];
    const float* Ws       = (const float*)d_in[3];
    const float* att_src  = (const float*)d_in[4];
    const float* att_dst  = (const float*)d_in[5];
    const float* conv_bias= (const float*)d_in[6];
    const float* gn_w     = (const float*)d_in[7];
    const float* gn_b     = (const float*)d_in[8];
    const float* gn_ms    = (const float*)d_in[9];
    const float* W1       = (const float*)d_in[10];
    const float* b1       = (const float*)d_in[11];
    const float* W2       = (const float*)d_in[12];
    const float* b2       = (const float*)d_in[13];
    float* out = (float*)d_out;

    const int n = in_sizes[2];       // 100000
    const int e = in_sizes[1] / 2;   // 600000
    const int* src = ei;
    const int* dst = ei + e;
    const int nbk = (n + 511) >> 9;  // 512-node buckets (n <= 262144 for ebuf packing)

    char* ws = (char*)d_ws;
    unsigned short* hWb = (unsigned short*)ws;                    // n*128 bf16
    unsigned short* hb  = hWb + (size_t)n * HD;                   // n*128 bf16
    float* a_s    = (float*)(hb + (size_t)n * HD);                // n
    float* a_d    = a_s + n;                                      // n
    float* alpha  = a_d + n;                                      // 128
    float* beta   = alpha + HD;                                   // 128
    float* pooled4= beta + HD;                                    // 4*GG*128
    float* part   = pooled4 + 4 * GG * HD;                        // CSB*256
    unsigned short* Wt = (unsigned short*)(part + CSB * 256);     // 3*128*128
    int* offs     = (int*)(Wt + 3 * 16384);                       // n+1
    int* esrc     = offs + n + 1;                                 // e
    int* ebuf     = esrc + e;                                     // e
    int* bcnt     = ebuf + e;                                     // 513
    int* bbase    = bcnt + 513;                                   // 514
    int* bcur     = bbase + 514;                                  // 513

    // ---- init (weights->bf16 transposed + zero bucket counters) ----
    k_init<<<192, 256, 0, stream>>>(Ws, Wt, bcnt);
    // ---- bucketed CSR build ----
    k_bcount<<<256, 256, 0, stream>>>(dst, bcnt, e);
    k_bscan<<<1, 512, 0, stream>>>(bcnt, bbase, bcur, offs, nbk, n, e);
    k_part<<<256, 256, 0, stream>>>(src, dst, bcur, ebuf, e);
    k_bscatter<<<nbk, 256, 0, stream>>>(ebuf, bbase, offs, esrc, n);

    // ---- GAT layers ----
    for (int l = 0; l < 3; ++l) {
        if (l == 0) {
            k_gemm_a32<<<(n + 63) / 64, 256, 0, stream>>>(
                x, Wt, att_src, att_dst, hWb, a_s, a_d, n);
        } else {
            k_gemm_a16<<<(n + 63) / 64, 256, 0, stream>>>(
                hb, Wt + l * 16384, att_src + l * HD, att_dst + l * HD,
                alpha, beta, hWb, a_s, a_d, n);
        }
        k_agg<<<(n + 3) / 4, 256, 0, stream>>>(hWb, offs, esrc, a_s, a_d,
                                               conv_bias + l * HD, hb, n);
        if (l < 2) {
            k_colstat6<<<CSB, 256, 0, stream>>>(hb, part, n);
            k_colfin<<<1, 256, 0, stream>>>(part, gn_w + l * HD, gn_b + l * HD,
                                            gn_ms + l * HD, alpha, beta, 1.0f / n);
        }
    }

    // ---- pool + MLP ----
    k_pool<<<4 * GG, 256, 0, stream>>>(hb, batch, pooled4, n);
    k_mlp<<<GG, HD, 0, stream>>>(pooled4, W1, b1, W2, b2, out);
}